// Round 1
// baseline (465.046 us; speedup 1.0000x reference)
//
#include <hip/hip_runtime.h>
#include <hip/hip_bf16.h>

#define B_ 4
#define T_ 2048
#define C_ 1024
#define H_ 16
#define D_ 64
#define M_ (B_ * T_)   // 8192
#define N3_ (3 * C_)   // 3072

typedef __attribute__((ext_vector_type(4))) float f32x4;
typedef __attribute__((ext_vector_type(8))) short bf16x8;

__device__ __forceinline__ ushort f2bf(float f) {
  union { float f; unsigned u; } v; v.f = f;
  unsigned r = v.u + 0x7fffu + ((v.u >> 16) & 1u);
  return (ushort)(r >> 16);
}

// ---------------- cast f32 -> bf16 (vectorized) ----------------
__global__ void cvt_bf16_kernel(const float* __restrict__ in, ushort* __restrict__ out, int n4) {
  int i = blockIdx.x * blockDim.x + threadIdx.x;
  int stride = gridDim.x * blockDim.x;
  for (; i < n4; i += stride) {
    float4 v = reinterpret_cast<const float4*>(in)[i];
    ushort4 o;
    o.x = f2bf(v.x); o.y = f2bf(v.y); o.z = f2bf(v.z); o.w = f2bf(v.w);
    reinterpret_cast<ushort4*>(out)[i] = o;
  }
}

// ------------- transpose + cast: in[K][N] f32 -> out[N][K] bf16 -------------
__global__ __launch_bounds__(256) void transpose_cvt_kernel(const float* __restrict__ in,
                                                            ushort* __restrict__ out,
                                                            int K, int N) {
  __shared__ float tile[64][65];
  int k0 = blockIdx.y * 64, n0 = blockIdx.x * 64;
  int t = threadIdx.x;
  int rr = t >> 6, cc = t & 63;
#pragma unroll
  for (int i = 0; i < 16; ++i) {
    int r = i * 4 + rr;
    tile[r][cc] = in[(size_t)(k0 + r) * N + n0 + cc];
  }
  __syncthreads();
#pragma unroll
  for (int i = 0; i < 16; ++i) {
    int r = i * 4 + rr;  // r = n offset, cc = k offset
    out[(size_t)(n0 + r) * K + k0 + cc] = f2bf(tile[cc][r]);
  }
}

// ---------------- QKV GEMM: qkv = x @ w_qkv + b, scatter into q/k/vT ----------------
// A [M][1024] bf16 k-contig, Bt [3072][1024] bf16 k-contig.
__global__ __launch_bounds__(256) void gemm_qkv_kernel(const ushort* __restrict__ A,
                                                       const ushort* __restrict__ Bt,
                                                       const float* __restrict__ bias,
                                                       ushort* __restrict__ qb,
                                                       ushort* __restrict__ kb,
                                                       ushort* __restrict__ vT) {
  __shared__ __align__(16) ushort As[128][40];
  __shared__ __align__(16) ushort Bs[128][40];
  const int tid = threadIdx.x;
  const int wid = tid >> 6, lane = tid & 63;
  const int wm = wid >> 1, wn = wid & 1;
  const int lr = lane & 15, lg = lane >> 4;
  const int bm = blockIdx.y * 128, bn = blockIdx.x * 128;
  f32x4 acc[4][4] = {};
  for (int k0 = 0; k0 < 1024; k0 += 32) {
#pragma unroll
    for (int p = 0; p < 2; ++p) {
      int idx = p * 256 + tid;
      int r = idx >> 2, c = (idx & 3) * 8;
      *(uint4*)&As[r][c] = *(const uint4*)&A[(size_t)(bm + r) * 1024 + k0 + c];
      *(uint4*)&Bs[r][c] = *(const uint4*)&Bt[(size_t)(bn + r) * 1024 + k0 + c];
    }
    __syncthreads();
    bf16x8 af[4], bfr[4];
#pragma unroll
    for (int f = 0; f < 4; ++f) {
      af[f]  = *(const bf16x8*)&As[wm * 64 + f * 16 + lr][lg * 8];
      bfr[f] = *(const bf16x8*)&Bs[wn * 64 + f * 16 + lr][lg * 8];
    }
#pragma unroll
    for (int fm = 0; fm < 4; ++fm)
#pragma unroll
      for (int fn = 0; fn < 4; ++fn)
        acc[fm][fn] = __builtin_amdgcn_mfma_f32_16x16x32_bf16(af[fm], bfr[fn], acc[fm][fn], 0, 0, 0);
    __syncthreads();
  }
#pragma unroll
  for (int fm = 0; fm < 4; ++fm)
#pragma unroll
    for (int fn = 0; fn < 4; ++fn)
#pragma unroll
      for (int r = 0; r < 4; ++r) {
        int m = bm + wm * 64 + fm * 16 + lg * 4 + r;
        int n = bn + wn * 64 + fn * 16 + lr;
        float val = acc[fm][fn][r] + bias[n];
        ushort bv = f2bf(val);
        int part = n >> 10, cch = n & 1023;
        int h = cch >> 6, d = cch & 63;
        int bb = m >> 11, t = m & 2047;
        size_t bh = (size_t)bb * H_ + h;
        if (part == 0)      qb[(bh * T_ + t) * D_ + d] = bv;
        else if (part == 1) kb[(bh * T_ + t) * D_ + d] = bv;
        else                vT[(bh * D_ + d) * T_ + t] = bv;
      }
}

// ---------------- Proj GEMM: out = y @ w_proj + b (f32 out) ----------------
__global__ __launch_bounds__(256) void gemm_proj_kernel(const ushort* __restrict__ A,
                                                        const ushort* __restrict__ Bt,
                                                        const float* __restrict__ bias,
                                                        float* __restrict__ out) {
  __shared__ __align__(16) ushort As[128][40];
  __shared__ __align__(16) ushort Bs[128][40];
  const int tid = threadIdx.x;
  const int wid = tid >> 6, lane = tid & 63;
  const int wm = wid >> 1, wn = wid & 1;
  const int lr = lane & 15, lg = lane >> 4;
  const int bm = blockIdx.y * 128, bn = blockIdx.x * 128;
  f32x4 acc[4][4] = {};
  for (int k0 = 0; k0 < 1024; k0 += 32) {
#pragma unroll
    for (int p = 0; p < 2; ++p) {
      int idx = p * 256 + tid;
      int r = idx >> 2, c = (idx & 3) * 8;
      *(uint4*)&As[r][c] = *(const uint4*)&A[(size_t)(bm + r) * 1024 + k0 + c];
      *(uint4*)&Bs[r][c] = *(const uint4*)&Bt[(size_t)(bn + r) * 1024 + k0 + c];
    }
    __syncthreads();
    bf16x8 af[4], bfr[4];
#pragma unroll
    for (int f = 0; f < 4; ++f) {
      af[f]  = *(const bf16x8*)&As[wm * 64 + f * 16 + lr][lg * 8];
      bfr[f] = *(const bf16x8*)&Bs[wn * 64 + f * 16 + lr][lg * 8];
    }
#pragma unroll
    for (int fm = 0; fm < 4; ++fm)
#pragma unroll
      for (int fn = 0; fn < 4; ++fn)
        acc[fm][fn] = __builtin_amdgcn_mfma_f32_16x16x32_bf16(af[fm], bfr[fn], acc[fm][fn], 0, 0, 0);
    __syncthreads();
  }
#pragma unroll
  for (int fm = 0; fm < 4; ++fm)
#pragma unroll
    for (int fn = 0; fn < 4; ++fn)
#pragma unroll
      for (int r = 0; r < 4; ++r) {
        int m = bm + wm * 64 + fm * 16 + lg * 4 + r;
        int n = bn + wn * 64 + fn * 16 + lr;
        out[(size_t)m * C_ + n] = acc[fm][fn][r] + bias[n];
      }
}

// ---------------- Flash attention (causal), 64 q-rows per block ----------------
// q,k: [BH][T][D] bf16; vT: [BH][D][T] bf16; yb out: [B][T][H*D] bf16
__global__ __launch_bounds__(256) void attn_kernel(const ushort* __restrict__ qb,
                                                   const ushort* __restrict__ kb,
                                                   const ushort* __restrict__ vT,
                                                   ushort* __restrict__ yb) {
  __shared__ __align__(16) ushort Ks[64][72];
  __shared__ __align__(16) ushort Vs[64][72];
  __shared__ __align__(16) ushort Ps[4][16][72];
  const int qt = blockIdx.x, bh = blockIdx.y;
  const int tid = threadIdx.x, wid = tid >> 6, lane = tid & 63;
  const int lr = lane & 15, lg = lane >> 4;
  const ushort* Q  = qb + (size_t)bh * T_ * D_;
  const ushort* Kp = kb + (size_t)bh * T_ * D_;
  const ushort* Vp = vT + (size_t)bh * D_ * T_;
  const int q0 = qt * 64;
  const int qw = q0 + wid * 16;
  bf16x8 qf[2];
  qf[0] = *(const bf16x8*)&Q[(size_t)(qw + lr) * D_ + lg * 8];
  qf[1] = *(const bf16x8*)&Q[(size_t)(qw + lr) * D_ + 32 + lg * 8];
  float mr[4], lsum[4];
  f32x4 o[4] = {};
#pragma unroll
  for (int r = 0; r < 4; ++r) { mr[r] = -1e30f; lsum[r] = 0.f; }
  for (int kt = 0; kt <= qt; ++kt) {
    int k0 = kt * 64;
#pragma unroll
    for (int p = 0; p < 2; ++p) {
      int idx = p * 256 + tid;
      int r = idx >> 3, c = (idx & 7) * 8;
      *(uint4*)&Ks[r][c] = *(const uint4*)&Kp[(size_t)(k0 + r) * D_ + c];
      *(uint4*)&Vs[r][c] = *(const uint4*)&Vp[(size_t)r * T_ + k0 + c];
    }
    __syncthreads();
    // S = Q K^T  (rows q, cols keys)
    f32x4 s[4];
#pragma unroll
    for (int fk = 0; fk < 4; ++fk) {
      f32x4 a = {};
#pragma unroll
      for (int ks = 0; ks < 2; ++ks) {
        bf16x8 kf = *(const bf16x8*)&Ks[fk * 16 + lr][ks * 32 + lg * 8];
        a = __builtin_amdgcn_mfma_f32_16x16x32_bf16(qf[ks], kf, a, 0, 0, 0);
      }
#pragma unroll
      for (int r = 0; r < 4; ++r) s[fk][r] = a[r] * 0.125f;
    }
    if (kt == qt) {
#pragma unroll
      for (int fk = 0; fk < 4; ++fk)
#pragma unroll
        for (int r = 0; r < 4; ++r)
          if (k0 + fk * 16 + lr > qw + lg * 4 + r) s[fk][r] = -1e30f;
    }
    // online softmax per q-row (row = lg*4 + r; 16 key-cols across lanes, 4 across frags)
#pragma unroll
    for (int r = 0; r < 4; ++r) {
      float v = fmaxf(fmaxf(s[0][r], s[1][r]), fmaxf(s[2][r], s[3][r]));
      v = fmaxf(v, __shfl_xor(v, 1));
      v = fmaxf(v, __shfl_xor(v, 2));
      v = fmaxf(v, __shfl_xor(v, 4));
      v = fmaxf(v, __shfl_xor(v, 8));
      float nm = fmaxf(mr[r], v);
      float sc = __expf(mr[r] - nm);
      mr[r] = nm;
      lsum[r] *= sc;
#pragma unroll
      for (int fd = 0; fd < 4; ++fd) o[fd][r] *= sc;
      float ps = 0.f;
#pragma unroll
      for (int fk = 0; fk < 4; ++fk) {
        float p = __expf(s[fk][r] - nm);
        s[fk][r] = p;
        ps += p;
      }
      ps += __shfl_xor(ps, 1);
      ps += __shfl_xor(ps, 2);
      ps += __shfl_xor(ps, 4);
      ps += __shfl_xor(ps, 8);
      lsum[r] += ps;
#pragma unroll
      for (int fk = 0; fk < 4; ++fk)
        Ps[wid][lg * 4 + r][fk * 16 + lr] = f2bf(s[fk][r]);
    }
    // O += P @ V   (A = P from LDS in A-layout, B = V^T slices)
    bf16x8 pa[2];
    pa[0] = *(const bf16x8*)&Ps[wid][lr][lg * 8];
    pa[1] = *(const bf16x8*)&Ps[wid][lr][32 + lg * 8];
#pragma unroll
    for (int fd = 0; fd < 4; ++fd)
#pragma unroll
      for (int ks = 0; ks < 2; ++ks) {
        bf16x8 vf = *(const bf16x8*)&Vs[fd * 16 + lr][ks * 32 + lg * 8];
        o[fd] = __builtin_amdgcn_mfma_f32_16x16x32_bf16(pa[ks], vf, o[fd], 0, 0, 0);
      }
    __syncthreads();
  }
  const int bb = bh >> 4, h = bh & 15;
#pragma unroll
  for (int fd = 0; fd < 4; ++fd)
#pragma unroll
    for (int r = 0; r < 4; ++r) {
      int t = qw + lg * 4 + r;
      float val = o[fd][r] / lsum[r];
      yb[((size_t)(bb * T_ + t)) * C_ + h * D_ + fd * 16 + lr] = f2bf(val);
    }
}

// ---------------------------------------------------------------------------
extern "C" void kernel_launch(void* const* d_in, const int* in_sizes, int n_in,
                              void* d_out, int out_size, void* d_ws, size_t ws_size,
                              hipStream_t stream) {
  const float* x      = (const float*)d_in[0];
  const float* w_qkv  = (const float*)d_in[1];
  const float* b_qkv  = (const float*)d_in[2];
  const float* w_proj = (const float*)d_in[3];
  const float* b_proj = (const float*)d_in[4];
  float* out = (float*)d_out;

  char* ws = (char*)d_ws;
  const size_t MB = 1024 * 1024;
  ushort* xb     = (ushort*)(ws);                 // 16 MB  [8192][1024]
  ushort* wqkvT  = (ushort*)(ws + 16 * MB);       // 6  MB  [3072][1024]
  ushort* wprojT = (ushort*)(ws + 22 * MB);       // 2  MB  [1024][1024]
  ushort* qbuf   = (ushort*)(ws + 24 * MB);       // 16 MB  [64][2048][64]
  ushort* kbuf   = (ushort*)(ws + 40 * MB);       // 16 MB  [64][2048][64]
  ushort* vTbuf  = (ushort*)(ws + 56 * MB);       // 16 MB  [64][64][2048]
  ushort* ybuf   = (ushort*)(ws + 72 * MB);       // 16 MB  [8192][1024]

  cvt_bf16_kernel<<<2048, 256, 0, stream>>>(x, xb, M_ * C_ / 4);
  transpose_cvt_kernel<<<dim3(N3_ / 64, C_ / 64), 256, 0, stream>>>(w_qkv, wqkvT, C_, N3_);
  transpose_cvt_kernel<<<dim3(C_ / 64, C_ / 64), 256, 0, stream>>>(w_proj, wprojT, C_, C_);
  gemm_qkv_kernel<<<dim3(N3_ / 128, M_ / 128), 256, 0, stream>>>(xb, wqkvT, b_qkv, qbuf, kbuf, vTbuf);
  attn_kernel<<<dim3(T_ / 64, B_ * H_), 256, 0, stream>>>(qbuf, kbuf, vTbuf, ybuf);
  gemm_proj_kernel<<<dim3(C_ / 128, M_ / 128), 256, 0, stream>>>(ybuf, wprojT, b_proj, out);
}

// Round 2
// 333.506 us; speedup vs baseline: 1.3944x; 1.3944x over previous
//
#include <hip/hip_runtime.h>
#include <hip/hip_bf16.h>

#define B_ 4
#define T_ 2048
#define C_ 1024
#define H_ 16
#define D_ 64
#define M_ (B_ * T_)   // 8192
#define N3_ (3 * C_)   // 3072

typedef __attribute__((ext_vector_type(4))) float f32x4;
typedef __attribute__((ext_vector_type(8))) short bf16x8;

__device__ __forceinline__ ushort f2bf(float f) {
  union { float f; unsigned u; } v; v.f = f;
  unsigned r = v.u + 0x7fffu + ((v.u >> 16) & 1u);
  return (ushort)(r >> 16);
}

// async global->LDS, 16B per lane. lds ptr must be wave-uniform base; lane i lands at base + i*16.
__device__ __forceinline__ void gload_lds16(const ushort* g, ushort* l) {
  __builtin_amdgcn_global_load_lds((const __attribute__((address_space(1))) void*)g,
                                   (__attribute__((address_space(3))) void*)l, 16, 0, 0);
}

// ---------------- cast f32 -> bf16 (vectorized) ----------------
__global__ void cvt_bf16_kernel(const float* __restrict__ in, ushort* __restrict__ out, int n4) {
  int i = blockIdx.x * blockDim.x + threadIdx.x;
  int stride = gridDim.x * blockDim.x;
  for (; i < n4; i += stride) {
    float4 v = reinterpret_cast<const float4*>(in)[i];
    ushort4 o;
    o.x = f2bf(v.x); o.y = f2bf(v.y); o.z = f2bf(v.z); o.w = f2bf(v.w);
    reinterpret_cast<ushort4*>(out)[i] = o;
  }
}

// ------------- transpose + cast: in[K][N] f32 -> out[N][K] bf16 -------------
__global__ __launch_bounds__(256) void transpose_cvt_kernel(const float* __restrict__ in,
                                                            ushort* __restrict__ out,
                                                            int K, int N) {
  __shared__ float tile[64][65];
  int k0 = blockIdx.y * 64, n0 = blockIdx.x * 64;
  int t = threadIdx.x;
  int rr = t >> 6, cc = t & 63;
#pragma unroll
  for (int i = 0; i < 16; ++i) {
    int r = i * 4 + rr;
    tile[r][cc] = in[(size_t)(k0 + r) * N + n0 + cc];
  }
  __syncthreads();
#pragma unroll
  for (int i = 0; i < 16; ++i) {
    int r = i * 4 + rr;  // r = n offset, cc = k offset
    out[(size_t)(n0 + r) * K + k0 + cc] = f2bf(tile[cc][r]);
  }
}

// ---------------- QKV GEMM (m97 structure): qkv = x @ w_qkv + b -> q/k/vT ----------------
// A [M][1024] bf16 k-contig, Bt [3072][1024] bf16 k-contig.
// q,k out: [BH][T][D]; v out transposed: [BH][D][T]
__global__ __launch_bounds__(256) void gemm_qkv_kernel(const ushort* __restrict__ A,
                                                       const ushort* __restrict__ Bt,
                                                       const float* __restrict__ bias,
                                                       ushort* __restrict__ qb,
                                                       ushort* __restrict__ kb,
                                                       ushort* __restrict__ vT) {
  __shared__ __align__(16) ushort As[128 * 32];
  __shared__ __align__(16) ushort Bs[128 * 32];
  const int tid = threadIdx.x;
  const int wid = tid >> 6, lane = tid & 63;
  const int wm = wid >> 1, wn = wid & 1;
  const int lr = lane & 15, lg = lane >> 4;
  const int bm = blockIdx.y * 128, bn = blockIdx.x * 128;
  const int srow = wid * 32 + (lane >> 2);          // staging source row (this lane)
  const int scol = (lane & 3) * 8;                  // staging source col (ushorts)
  ushort* lA = &As[wid * 32 * 32];                  // wave-uniform LDS dest base
  ushort* lB = &Bs[wid * 32 * 32];
  const ushort* gA0 = A  + (size_t)(bm + srow) * 1024 + scol;
  const ushort* gB0 = Bt + (size_t)(bn + srow) * 1024 + scol;
  f32x4 acc[4][4] = {};
  for (int k0 = 0; k0 < 1024; k0 += 32) {
    gload_lds16(gA0 + k0, lA);
    gload_lds16(gA0 + k0 + 16 * 1024, lA + 16 * 32);
    gload_lds16(gB0 + k0, lB);
    gload_lds16(gB0 + k0 + 16 * 1024, lB + 16 * 32);
    __syncthreads();
    bf16x8 af[4], bfr[4];
#pragma unroll
    for (int f = 0; f < 4; ++f) {
      af[f]  = *(const bf16x8*)&As[(wm * 64 + f * 16 + lr) * 32 + lg * 8];
      bfr[f] = *(const bf16x8*)&Bs[(wn * 64 + f * 16 + lr) * 32 + lg * 8];
    }
#pragma unroll
    for (int fm = 0; fm < 4; ++fm)
#pragma unroll
      for (int fn = 0; fn < 4; ++fn)
        acc[fm][fn] = __builtin_amdgcn_mfma_f32_16x16x32_bf16(af[fm], bfr[fn], acc[fm][fn], 0, 0, 0);
    __syncthreads();
  }
#pragma unroll
  for (int fm = 0; fm < 4; ++fm)
#pragma unroll
    for (int fn = 0; fn < 4; ++fn) {
      int m0 = bm + wm * 64 + fm * 16 + lg * 4;      // 4 consecutive m rows
      int n  = bn + wn * 64 + fn * 16 + lr;
      float b = bias[n];
      int part = n >> 10, cch = n & 1023;
      int h = cch >> 6, d = cch & 63;
      int bb = m0 >> 11, t = m0 & 2047;              // t..t+3 same batch (aligned)
      size_t bh = (size_t)bb * H_ + h;
      if (part == 2) {
        ushort4 pv;
        pv.x = f2bf(acc[fm][fn][0] + b);
        pv.y = f2bf(acc[fm][fn][1] + b);
        pv.z = f2bf(acc[fm][fn][2] + b);
        pv.w = f2bf(acc[fm][fn][3] + b);
        *(ushort4*)&vT[(bh * D_ + d) * T_ + t] = pv;  // 4 consecutive t -> 8B store
      } else {
        ushort* dst = (part == 0) ? qb : kb;
#pragma unroll
        for (int r = 0; r < 4; ++r)
          dst[(bh * T_ + t + r) * D_ + d] = f2bf(acc[fm][fn][r] + b);
      }
    }
}

// ---------------- Proj GEMM (m97 structure): out = y @ w_proj + b (f32 out) ----------------
__global__ __launch_bounds__(256) void gemm_proj_kernel(const ushort* __restrict__ A,
                                                        const ushort* __restrict__ Bt,
                                                        const float* __restrict__ bias,
                                                        float* __restrict__ out) {
  __shared__ __align__(16) ushort As[128 * 32];
  __shared__ __align__(16) ushort Bs[128 * 32];
  const int tid = threadIdx.x;
  const int wid = tid >> 6, lane = tid & 63;
  const int wm = wid >> 1, wn = wid & 1;
  const int lr = lane & 15, lg = lane >> 4;
  const int bm = blockIdx.y * 128, bn = blockIdx.x * 128;
  const int srow = wid * 32 + (lane >> 2);
  const int scol = (lane & 3) * 8;
  ushort* lA = &As[wid * 32 * 32];
  ushort* lB = &Bs[wid * 32 * 32];
  const ushort* gA0 = A  + (size_t)(bm + srow) * 1024 + scol;
  const ushort* gB0 = Bt + (size_t)(bn + srow) * 1024 + scol;
  f32x4 acc[4][4] = {};
  for (int k0 = 0; k0 < 1024; k0 += 32) {
    gload_lds16(gA0 + k0, lA);
    gload_lds16(gA0 + k0 + 16 * 1024, lA + 16 * 32);
    gload_lds16(gB0 + k0, lB);
    gload_lds16(gB0 + k0 + 16 * 1024, lB + 16 * 32);
    __syncthreads();
    bf16x8 af[4], bfr[4];
#pragma unroll
    for (int f = 0; f < 4; ++f) {
      af[f]  = *(const bf16x8*)&As[(wm * 64 + f * 16 + lr) * 32 + lg * 8];
      bfr[f] = *(const bf16x8*)&Bs[(wn * 64 + f * 16 + lr) * 32 + lg * 8];
    }
#pragma unroll
    for (int fm = 0; fm < 4; ++fm)
#pragma unroll
      for (int fn = 0; fn < 4; ++fn)
        acc[fm][fn] = __builtin_amdgcn_mfma_f32_16x16x32_bf16(af[fm], bfr[fn], acc[fm][fn], 0, 0, 0);
    __syncthreads();
  }
#pragma unroll
  for (int fm = 0; fm < 4; ++fm)
#pragma unroll
    for (int fn = 0; fn < 4; ++fn)
#pragma unroll
      for (int r = 0; r < 4; ++r) {
        int m = bm + wm * 64 + fm * 16 + lg * 4 + r;
        int n = bn + wn * 64 + fn * 16 + lr;
        out[(size_t)m * C_ + n] = acc[fm][fn][r] + bias[n];
      }
}

// ---------------- Flash attention (causal), paired q-tiles for load balance ----------------
// q,k: [BH][T][D] bf16; vT: [BH][D][T] bf16; yb out: [B][T][H*D] bf16
// block x = 0..15: processes q-tile x and q-tile 31-x (uniform 33 k-tiles/block)
__global__ __launch_bounds__(256) void attn_kernel(const ushort* __restrict__ qb,
                                                   const ushort* __restrict__ kb,
                                                   const ushort* __restrict__ vT,
                                                   ushort* __restrict__ yb) {
  __shared__ __align__(16) ushort Ks[64][72];
  __shared__ __align__(16) ushort Vs[64][72];
  __shared__ __align__(16) ushort Ps[4][16][72];
  const int bx = blockIdx.x, bh = blockIdx.y;
  const int tid = threadIdx.x, wid = tid >> 6, lane = tid & 63;
  const int lr = lane & 15, lg = lane >> 4;
  const ushort* Q  = qb + (size_t)bh * T_ * D_;
  const ushort* Kp = kb + (size_t)bh * T_ * D_;
  const ushort* Vp = vT + (size_t)bh * D_ * T_;
  const int bb = bh >> 4, h = bh & 15;

  for (int pass = 0; pass < 2; ++pass) {
    const int qt = pass == 0 ? bx : (T_ / 64 - 1) - bx;
    const int q0 = qt * 64;
    const int qw = q0 + wid * 16;
    bf16x8 qf[2];
    qf[0] = *(const bf16x8*)&Q[(size_t)(qw + lr) * D_ + lg * 8];
    qf[1] = *(const bf16x8*)&Q[(size_t)(qw + lr) * D_ + 32 + lg * 8];
    float mr[4], lsum[4];
    f32x4 o[4] = {};
#pragma unroll
    for (int r = 0; r < 4; ++r) { mr[r] = -1e30f; lsum[r] = 0.f; }
    for (int kt = 0; kt <= qt; ++kt) {
      int k0 = kt * 64;
#pragma unroll
      for (int p = 0; p < 2; ++p) {
        int idx = p * 256 + tid;
        int r = idx >> 3, c = (idx & 7) * 8;
        *(uint4*)&Ks[r][c] = *(const uint4*)&Kp[(size_t)(k0 + r) * D_ + c];
        *(uint4*)&Vs[r][c] = *(const uint4*)&Vp[(size_t)r * T_ + k0 + c];
      }
      __syncthreads();
      // S = Q K^T  (rows q, cols keys)
      f32x4 s[4];
#pragma unroll
      for (int fk = 0; fk < 4; ++fk) {
        f32x4 a = {};
#pragma unroll
        for (int ks = 0; ks < 2; ++ks) {
          bf16x8 kf = *(const bf16x8*)&Ks[fk * 16 + lr][ks * 32 + lg * 8];
          a = __builtin_amdgcn_mfma_f32_16x16x32_bf16(qf[ks], kf, a, 0, 0, 0);
        }
#pragma unroll
        for (int r = 0; r < 4; ++r) s[fk][r] = a[r] * 0.125f;
      }
      if (kt == qt) {
#pragma unroll
        for (int fk = 0; fk < 4; ++fk)
#pragma unroll
          for (int r = 0; r < 4; ++r)
            if (k0 + fk * 16 + lr > qw + lg * 4 + r) s[fk][r] = -1e30f;
      }
      // online softmax per q-row (row = lg*4 + r; 16 key-cols across lanes, 4 across frags)
#pragma unroll
      for (int r = 0; r < 4; ++r) {
        float v = fmaxf(fmaxf(s[0][r], s[1][r]), fmaxf(s[2][r], s[3][r]));
        v = fmaxf(v, __shfl_xor(v, 1));
        v = fmaxf(v, __shfl_xor(v, 2));
        v = fmaxf(v, __shfl_xor(v, 4));
        v = fmaxf(v, __shfl_xor(v, 8));
        float nm = fmaxf(mr[r], v);
        float sc = __expf(mr[r] - nm);
        mr[r] = nm;
        lsum[r] *= sc;
#pragma unroll
        for (int fd = 0; fd < 4; ++fd) o[fd][r] *= sc;
        float ps = 0.f;
#pragma unroll
        for (int fk = 0; fk < 4; ++fk) {
          float p = __expf(s[fk][r] - nm);
          s[fk][r] = p;
          ps += p;
        }
        ps += __shfl_xor(ps, 1);
        ps += __shfl_xor(ps, 2);
        ps += __shfl_xor(ps, 4);
        ps += __shfl_xor(ps, 8);
        lsum[r] += ps;
#pragma unroll
        for (int fk = 0; fk < 4; ++fk)
          Ps[wid][lg * 4 + r][fk * 16 + lr] = f2bf(s[fk][r]);
      }
      // O += P @ V   (A = P from LDS in A-layout, B = V^T slices)
      bf16x8 pa[2];
      pa[0] = *(const bf16x8*)&Ps[wid][lr][lg * 8];
      pa[1] = *(const bf16x8*)&Ps[wid][lr][32 + lg * 8];
#pragma unroll
      for (int fd = 0; fd < 4; ++fd)
#pragma unroll
        for (int ks = 0; ks < 2; ++ks) {
          bf16x8 vf = *(const bf16x8*)&Vs[fd * 16 + lr][ks * 32 + lg * 8];
          o[fd] = __builtin_amdgcn_mfma_f32_16x16x32_bf16(pa[ks], vf, o[fd], 0, 0, 0);
        }
      __syncthreads();
    }
#pragma unroll
    for (int fd = 0; fd < 4; ++fd)
#pragma unroll
      for (int r = 0; r < 4; ++r) {
        int t = qw + lg * 4 + r;
        float val = o[fd][r] / lsum[r];
        yb[((size_t)(bb * T_ + t)) * C_ + h * D_ + fd * 16 + lr] = f2bf(val);
      }
  }
}

// ---------------------------------------------------------------------------
extern "C" void kernel_launch(void* const* d_in, const int* in_sizes, int n_in,
                              void* d_out, int out_size, void* d_ws, size_t ws_size,
                              hipStream_t stream) {
  const float* x      = (const float*)d_in[0];
  const float* w_qkv  = (const float*)d_in[1];
  const float* b_qkv  = (const float*)d_in[2];
  const float* w_proj = (const float*)d_in[3];
  const float* b_proj = (const float*)d_in[4];
  float* out = (float*)d_out;

  char* ws = (char*)d_ws;
  const size_t MB = 1024 * 1024;
  ushort* xb     = (ushort*)(ws);                 // 16 MB  [8192][1024]
  ushort* wqkvT  = (ushort*)(ws + 16 * MB);       // 6  MB  [3072][1024]
  ushort* wprojT = (ushort*)(ws + 22 * MB);       // 2  MB  [1024][1024]
  ushort* qbuf   = (ushort*)(ws + 24 * MB);       // 16 MB  [64][2048][64]
  ushort* kbuf   = (ushort*)(ws + 40 * MB);       // 16 MB  [64][2048][64]
  ushort* vTbuf  = (ushort*)(ws + 56 * MB);       // 16 MB  [64][64][2048]
  ushort* ybuf   = (ushort*)(ws + 72 * MB);       // 16 MB  [8192][1024]

  cvt_bf16_kernel<<<2048, 256, 0, stream>>>(x, xb, M_ * C_ / 4);
  transpose_cvt_kernel<<<dim3(N3_ / 64, C_ / 64), 256, 0, stream>>>(w_qkv, wqkvT, C_, N3_);
  transpose_cvt_kernel<<<dim3(C_ / 64, C_ / 64), 256, 0, stream>>>(w_proj, wprojT, C_, C_);
  gemm_qkv_kernel<<<dim3(N3_ / 128, M_ / 128), 256, 0, stream>>>(xb, wqkvT, b_qkv, qbuf, kbuf, vTbuf);
  attn_kernel<<<dim3(T_ / 128, B_ * H_), 256, 0, stream>>>(qbuf, kbuf, vTbuf, ybuf);
  gemm_proj_kernel<<<dim3(C_ / 128, M_ / 128), 256, 0, stream>>>(ybuf, wprojT, b_proj, out);
}